// Round 1
// baseline (46.514 us; speedup 1.0000x reference)
//
#include <hip/hip_runtime.h>
#include <stdint.h>

#define H 4
#define DB 64
#define EB 64
#define NQ 4096
#define NK 4096
#define NPOS 13
#define SIM_K 12
#define VAL_K 10
#define OUT_K 12

typedef unsigned long long u64;
typedef unsigned int u32;
typedef unsigned short u16;
typedef unsigned char u8;

// ---- workspace layout (bytes) ----
#define OFF_KPLO  0                         // NK u64   (enc bits packed)
#define OFF_KPHI  (OFF_KPLO + NK*8)         // NK u64   (pos bits packed, 13 bits)
#define OFF_DQ    (OFF_KPHI + NK*8)         // NQ u64   (dec bits packed)
#define OFF_AQ    (OFF_DQ + NQ*8)           // H*NQ u16 (addr_q per head,query)
#define OFF_AK    (OFF_AQ + H*NQ*2)         // H*NK u16 (addr_kp per head,key)
#define OFF_PRES  (OFF_AK + H*NK*2)         // H*4096 u8 (addr_q present flags)
#define OFF_VAL   (OFF_PRES + H*4096)       // H*64*64 u64 (val bits, [h][w][d])
#define OFF_RES   (OFF_VAL + (size_t)H*4096*8) // H*4096 u64 (agg d-mask per (h,addr_q))
#define WS_NEEDED (OFF_RES + (size_t)H*4096*8)

// K1: pack enc/dec bit rows into u64, pos bits, zero present flags.
__global__ void k1_pack(const int* __restrict__ dec_bits,
                        const int* __restrict__ enc_bits, u8* ws) {
    int t = blockIdx.x * blockDim.x + threadIdx.x;
    if (t >= NK) return;
    u64* kplo = (u64*)(ws + OFF_KPLO);
    u64* kphi = (u64*)(ws + OFF_KPHI);
    u64* dq   = (u64*)(ws + OFF_DQ);
    ((u32*)(ws + OFF_PRES))[t] = 0u;   // 4096*4B = 16KB = H*4096 u8
    const int4* er = (const int4*)(enc_bits + t * EB);
    const int4* dr = (const int4*)(dec_bits + t * DB);
    u64 lo = 0, dv = 0;
#pragma unroll
    for (int j = 0; j < 16; ++j) {
        int4 e = er[j];
        int4 d = dr[j];
        lo |= ((u64)(e.x & 1) << (4 * j)) | ((u64)(e.y & 1) << (4 * j + 1)) |
              ((u64)(e.z & 1) << (4 * j + 2)) | ((u64)(e.w & 1) << (4 * j + 3));
        dv |= ((u64)(d.x & 1) << (4 * j)) | ((u64)(d.y & 1) << (4 * j + 1)) |
              ((u64)(d.z & 1) << (4 * j + 2)) | ((u64)(d.w & 1) << (4 * j + 3));
    }
    kplo[t] = lo;
    dq[t] = dv;
    // kp bit (64+i) = pos_bits[t][i] = (t >> (12-i)) & 1  -> bit-reverse low 13 bits
    kphi[t] = (u64)(__brev((u32)t) >> 19);
}

// K2: addr_q (+present flag) and addr_kp for every head.
__global__ void k2_addr(const int* __restrict__ sim_conn, u8* ws) {
    int t = blockIdx.x * blockDim.x + threadIdx.x;  // 0 .. H*(NQ+NK)
    const u64* kplo = (const u64*)(ws + OFF_KPLO);
    const u64* kphi = (const u64*)(ws + OFF_KPHI);
    const u64* dq   = (const u64*)(ws + OFF_DQ);
    u16* aq = (u16*)(ws + OFF_AQ);
    u16* ak = (u16*)(ws + OFF_AK);
    u8*  pres = ws + OFF_PRES;
    if (t < H * NQ) {
        int h = t / NQ, q = t % NQ;
        u64 d = dq[q];
        int a = 0;
#pragma unroll
        for (int j = 0; j < SIM_K; ++j) {
            int c = sim_conn[h * SIM_K + j];
            if (c < DB) a |= (int)((d >> c) & 1ull) << j;
        }
        aq[t] = (u16)a;
        pres[h * 4096 + a] = 1;
    } else {
        int t2 = t - H * NQ;
        if (t2 >= H * NK) return;
        int h = t2 / NK, k = t2 % NK;
        u64 lo = kplo[k], hi = kphi[k];
        int a = 0;
#pragma unroll
        for (int j = 0; j < SIM_K; ++j) {
            int c = sim_conn[h * SIM_K + j];
            if (c >= DB) {
                int c2 = c - DB;
                int bit = (c2 < 64) ? (int)((lo >> c2) & 1ull)
                                    : (int)((hi >> (c2 - 64)) & 1ull);
                a |= bit << j;
            }
        }
        ak[t2] = (u16)a;
    }
}

// K3: val_bits[h][w][d] packed along k (64 keys per word); 4 threads per word
// each produce one 16-bit chunk.
__global__ void k3_val(const int* __restrict__ val_conn,
                       const float* __restrict__ val_table, u8* ws) {
    int t = blockIdx.x * blockDim.x + threadIdx.x;  // 0 .. H*64*64*4
    int c = t & 3, d = (t >> 2) & 63, w = (t >> 8) & 63, h = t >> 14;
    const u64* kplo = (const u64*)(ws + OFF_KPLO);
    const u64* kphi = (const u64*)(ws + OFF_KPHI);
    int conn[VAL_K];
#pragma unroll
    for (int j = 0; j < VAL_K; ++j) conn[j] = val_conn[(h * DB + d) * VAL_K + j];
    const float* row = val_table + ((h * DB + d) << VAL_K);
    u32 chunk = 0;
#pragma unroll 4
    for (int i = 0; i < 16; ++i) {
        int k = (w << 6) + (c << 4) + i;
        u64 lo = kplo[k], hi = kphi[k];
        int addr = 0;
#pragma unroll
        for (int j = 0; j < VAL_K; ++j) {
            int cc = conn[j];
            int bit = (cc < 64) ? (int)((lo >> cc) & 1ull)
                                : (int)((hi >> (cc - 64)) & 1ull);
            addr |= bit << j;
        }
        chunk |= (row[addr] > 0.5f ? 1u : 0u) << i;
    }
    ((u16*)(ws + OFF_VAL))[(((h << 12) + (w << 6) + d) << 2) + c] = (u16)chunk;
}

// K4: heavy phase, one 64-thread block per (h, addr_q) candidate; early-exit
// if that addr_q value never occurs. Generates att words via ballot, AND+popcount
// against val_bits, majority vote -> 64-bit agg mask in res[h][a].
__global__ void __launch_bounds__(64) k4_heavy(const float* __restrict__ sim_table,
                                               u8* ws) {
    int b = blockIdx.x;              // b = h*4096 + a
    if (!ws[OFF_PRES + b]) return;
    int h = b >> 12, a = b & 4095;
    int lane = threadIdx.x;

    __shared__ u8  simb[4096];
    __shared__ u16 akp[4096];
    __shared__ u64 vall[4096];       // [w][d]

    const float* st = sim_table + (h << 12);
    const u16* akg = (const u16*)(ws + OFF_AK) + (h << 12);
    const u64* vg  = (const u64*)(ws + OFF_VAL) + (h << 12);
#pragma unroll 4
    for (int i = 0; i < 64; ++i) {
        int idx = (i << 6) + lane;
        simb[idx] = st[idx] > 0.5f ? (u8)1 : (u8)0;
        akp[idx] = akg[idx];
        vall[idx] = vg[idx];
    }
    __syncthreads();

    u32 sums = 0, cnt = 0;
#pragma unroll 4
    for (int w = 0; w < 64; ++w) {
        int idx = (w << 6) + lane;
        int addr = a | (int)akp[idx];
        u64 m = __ballot(simb[addr] != 0);
        u64 v = vall[idx];
        sums += (u32)__popcll(m & v);
        cnt += (u32)__popcll(m);
    }
    int g = (cnt > 0u) && (2u * sums >= cnt);
    u64 gm = __ballot(g);
    if (lane == 0) ((u64*)(ws + OFF_RES))[b] = gm;
}

// K5: per (q,d): gather 12 bits from combined 256-bit agg vector, out_table lookup.
__global__ void k5_out(const int* __restrict__ out_conn,
                       const float* __restrict__ out_table,
                       const u8* __restrict__ ws, float* __restrict__ out) {
    int g = blockIdx.x * blockDim.x + threadIdx.x;  // 0 .. NQ*DB
    int q = g >> 6, d = g & 63;
    const u16* aq = (const u16*)(ws + OFF_AQ);
    const u64* res = (const u64*)(ws + OFF_RES);
    u64 c0 = res[0 * 4096 + aq[0 * NQ + q]];
    u64 c1 = res[1 * 4096 + aq[1 * NQ + q]];
    u64 c2 = res[2 * 4096 + aq[2 * NQ + q]];
    u64 c3 = res[3 * 4096 + aq[3 * NQ + q]];
    int addr = 0;
#pragma unroll
    for (int j = 0; j < OUT_K; ++j) {
        int c = out_conn[d * OUT_K + j];
        u64 word = (c & 128) ? ((c & 64) ? c3 : c2) : ((c & 64) ? c1 : c0);
        addr |= (int)((word >> (c & 63)) & 1ull) << j;
    }
    out[g] = out_table[(d << 12) + addr] > 0.5f ? 1.0f : 0.0f;
}

extern "C" void kernel_launch(void* const* d_in, const int* in_sizes, int n_in,
                              void* d_out, int out_size, void* d_ws, size_t ws_size,
                              hipStream_t stream) {
    const int*   dec_bits  = (const int*)d_in[0];
    const int*   enc_bits  = (const int*)d_in[1];
    const int*   sim_conn  = (const int*)d_in[2];
    const float* sim_table = (const float*)d_in[3];
    const int*   val_conn  = (const int*)d_in[4];
    const float* val_table = (const float*)d_in[5];
    const int*   out_conn  = (const int*)d_in[6];
    const float* out_table = (const float*)d_in[7];
    float* out = (float*)d_out;
    u8* ws = (u8*)d_ws;

    hipLaunchKernelGGL(k1_pack, dim3(NK / 256), dim3(256), 0, stream,
                       dec_bits, enc_bits, ws);
    hipLaunchKernelGGL(k2_addr, dim3((H * (NQ + NK)) / 256), dim3(256), 0, stream,
                       sim_conn, ws);
    hipLaunchKernelGGL(k3_val, dim3((H * 64 * 64 * 4) / 256), dim3(256), 0, stream,
                       val_conn, val_table, ws);
    hipLaunchKernelGGL(k4_heavy, dim3(H * 4096), dim3(64), 0, stream,
                       sim_table, ws);
    hipLaunchKernelGGL(k5_out, dim3((NQ * DB) / 256), dim3(256), 0, stream,
                       out_conn, out_table, ws, out);
}

// Round 2
// 42.200 us; speedup vs baseline: 1.1022x; 1.1022x over previous
//
#include <hip/hip_runtime.h>
#include <stdint.h>

#define H 4
#define DB 64
#define EB 64
#define NQ 4096
#define NK 4096
#define NPOS 13
#define SIM_K 12
#define VAL_K 10
#define OUT_K 12

typedef unsigned long long u64;
typedef unsigned int u32;
typedef unsigned short u16;
typedef unsigned char u8;

// ---- workspace layout (bytes) ----
#define OFF_KPLO  0u                          // NK u64 (enc bits)
#define OFF_KPHI  (OFF_KPLO + NK*8)           // NK u64 (pos bits)
#define OFF_AQ    (OFF_KPHI + NK*8)           // H*NQ u16
#define OFF_AK    (OFF_AQ + H*NQ*2)           // H*NK u16
#define OFF_PRESW (OFF_AK + H*NK*2)           // 512 u32 present bitmap
#define OFF_COUNT (OFF_PRESW + 512*4)         // 1 u32 (+pad)
#define OFF_LIST  (OFF_COUNT + 64)            // 16384 u32 task list
#define OFF_SIMB  (OFF_LIST + 16384*4)        // H*64 u64   (sim_table > 0.5 bits)
#define OFF_VALTB (OFF_SIMB + H*64*8)         // H*DB*16 u64 (val_table bits)
#define OFF_OUTTB (OFF_VALTB + H*DB*16*8)     // DB*64 u64  (out_table bits)
#define OFF_VAL   (OFF_OUTTB + DB*64*8)       // H*64*64 u64 (val bits per key-word)
#define OFF_RES   (OFF_VAL + H*4096*8)        // H*4096 u64 (agg d-mask)

// K_A: zero flags, binarize tables, pack bit-rows, compute addr_q/addr_kp.
__global__ void __launch_bounds__(256) kA(const int* __restrict__ dec_bits,
                                          const int* __restrict__ enc_bits,
                                          const int* __restrict__ sim_conn,
                                          const float* __restrict__ sim_table,
                                          const float* __restrict__ val_table,
                                          const float* __restrict__ out_table,
                                          u8* __restrict__ ws) {
    int t = blockIdx.x * 256 + threadIdx.x;   // 0..16383
    if (t < 512) ((u32*)(ws + OFF_PRESW))[t] = 0u;
    if (t == 512) *((u32*)(ws + OFF_COUNT)) = 0u;

    // ---- binarize tables via wave ballot (coalesced) ----
    {
        int wid = t >> 6, lane = t & 63;      // 256 waves total
        u64* sb = (u64*)(ws + OFF_SIMB);
        for (int wi = wid; wi < H * 64; wi += 256) {
            u64 m = __ballot(sim_table[wi * 64 + lane] > 0.5f);
            if (lane == 0) sb[wi] = m;
        }
        u64* vb = (u64*)(ws + OFF_VALTB);
        for (int wi = wid; wi < H * DB * 16; wi += 256) {
            u64 m = __ballot(val_table[wi * 64 + lane] > 0.5f);
            if (lane == 0) vb[wi] = m;
        }
        u64* ob = (u64*)(ws + OFF_OUTTB);
        for (int wi = wid; wi < DB * 64; wi += 256) {
            u64 m = __ballot(out_table[wi * 64 + lane] > 0.5f);
            if (lane == 0) ob[wi] = m;
        }
    }

    if (t < NK) {
        const int4* er = (const int4*)(enc_bits + t * EB);
        const int4* dr = (const int4*)(dec_bits + t * DB);
        u64 lo = 0, dv = 0;
#pragma unroll
        for (int j = 0; j < 16; ++j) {
            int4 e = er[j];
            int4 d = dr[j];
            lo |= ((u64)(e.x & 1) << (4 * j)) | ((u64)(e.y & 1) << (4 * j + 1)) |
                  ((u64)(e.z & 1) << (4 * j + 2)) | ((u64)(e.w & 1) << (4 * j + 3));
            dv |= ((u64)(d.x & 1) << (4 * j)) | ((u64)(d.y & 1) << (4 * j + 1)) |
                  ((u64)(d.z & 1) << (4 * j + 2)) | ((u64)(d.w & 1) << (4 * j + 3));
        }
        u64 hi = (u64)(__brev((u32)t) >> 19);  // pos bits
        ((u64*)(ws + OFF_KPLO))[t] = lo;
        ((u64*)(ws + OFF_KPHI))[t] = hi;
        u16* aq = (u16*)(ws + OFF_AQ);
        u16* ak = (u16*)(ws + OFF_AK);
#pragma unroll
        for (int h = 0; h < H; ++h) {
            int a_q = 0, a_k = 0;
#pragma unroll
            for (int j = 0; j < SIM_K; ++j) {
                int c = sim_conn[h * SIM_K + j];
                if (c < DB) {
                    a_q |= (int)((dv >> c) & 1ull) << j;
                } else {
                    int c2 = c - DB;
                    int bit = (c2 < 64) ? (int)((lo >> c2) & 1ull)
                                        : (int)((hi >> (c2 - 64)) & 1ull);
                    a_k |= bit << j;
                }
            }
            aq[h * NQ + t] = (u16)a_q;
            ak[h * NK + t] = (u16)a_k;
        }
    }
}

// K_B: mark+compact present (h,addr_q); compute val bits per (h, key-word, d)
// via LDS bit-tests on the binarized val table.
__global__ void __launch_bounds__(256) kB(const int* __restrict__ val_conn,
                                          u8* __restrict__ ws) {
    int b = blockIdx.x;                 // 0..255: h = b>>6, w = b&63
    int tid = threadIdx.x;
    int h = b >> 6, w = b & 63;

    // present-list compaction (uses aq written by kA)
    int gidx = b * 256 + tid;           // covers H*NQ = 16384
    if (gidx < H * NQ) {
        int a = ((const u16*)(ws + OFF_AQ))[gidx];
        int key = ((gidx >> 12) << 12) | a;
        u32* presw = (u32*)(ws + OFF_PRESW);
        u32 mask = 1u << (key & 31);
        u32 old = atomicOr(&presw[key >> 5], mask);
        if (!(old & mask)) {
            u32 p = atomicAdd((u32*)(ws + OFF_COUNT), 1u);
            ((u32*)(ws + OFF_LIST))[p] = (u32)key;
        }
    }

    __shared__ u64 klo_s[64], khi_s[64];
    __shared__ u64 vb_s[64 * 16];       // [d][16] bitmap words
    if (tid < 64) {
        klo_s[tid] = ((const u64*)(ws + OFF_KPLO))[w * 64 + tid];
        khi_s[tid] = ((const u64*)(ws + OFF_KPHI))[w * 64 + tid];
    }
    const u64* vbg = (const u64*)(ws + OFF_VALTB) + h * DB * 16;
    for (int i = tid; i < 64 * 16; i += 256) vb_s[i] = vbg[i];
    __syncthreads();

    int d = tid >> 2, c = tid & 3;
    int conn[VAL_K];
#pragma unroll
    for (int j = 0; j < VAL_K; ++j) conn[j] = val_conn[(h * DB + d) * VAL_K + j];
    u32 chunk = 0;
#pragma unroll 4
    for (int i = 0; i < 16; ++i) {
        int k = (c << 4) + i;
        u64 lo = klo_s[k], hi = khi_s[k];
        int addr = 0;
#pragma unroll
        for (int j = 0; j < VAL_K; ++j) {
            int cc = conn[j];
            int bit = (cc < 64) ? (int)((lo >> cc) & 1ull)
                                : (int)((hi >> (cc - 64)) & 1ull);
            addr |= bit << j;
        }
        u64 wv = vb_s[(d << 4) + (addr >> 6)];
        chunk |= (u32)((wv >> (addr & 63)) & 1ull) << i;
    }
    ((u16*)(ws + OFF_VAL))[(((h << 12) + (w << 6) + d) << 2) + c] = (u16)chunk;
}

// K_C: heavy phase over compacted task list; 256 threads (4 waves) per task.
__global__ void __launch_bounds__(256) kC(u8* __restrict__ ws) {
    __shared__ u16 akp_s[4096];
    __shared__ u64 val_s[4096];
    __shared__ u64 sim_s[64];
    __shared__ u32 sums_s[4][64];
    __shared__ u32 cnt_s[4];

    const u32 count = *(const u32*)(ws + OFF_COUNT);
    const u32* list = (const u32*)(ws + OFF_LIST);
    int tid = threadIdx.x;
    int wv = tid >> 6, lane = tid & 63;

    for (u32 i = blockIdx.x; i < count; i += gridDim.x) {
        u32 key = list[i];
        int h = (int)(key >> 12), a = (int)(key & 4095);
        const u64* akg = (const u64*)(ws + OFF_AK + (size_t)h * NK * 2);
        const u64* vg  = (const u64*)(ws + OFF_VAL) + ((size_t)h << 12);
        const u64* sg  = (const u64*)(ws + OFF_SIMB) + (h << 6);
        u64* akp_v = (u64*)akp_s;
#pragma unroll
        for (int j = 0; j < 4; ++j) akp_v[tid + 256 * j] = akg[tid + 256 * j];
#pragma unroll
        for (int j = 0; j < 16; ++j) val_s[tid + 256 * j] = vg[tid + 256 * j];
        if (tid < 64) sim_s[tid] = sg[tid];
        __syncthreads();

        u32 sums = 0, cnt = 0;
#pragma unroll
        for (int j = 0; j < 16; ++j) {
            int idx = (((wv << 4) + j) << 6) + lane;
            int addr = a | (int)akp_s[idx];
            int attb = (int)((sim_s[addr >> 6] >> (addr & 63)) & 1ull);
            u64 m = __ballot(attb);
            sums += (u32)__popcll(m & val_s[idx]);
            cnt += (u32)__popcll(m);
        }
        sums_s[wv][lane] = sums;
        if (lane == 0) cnt_s[wv] = cnt;
        __syncthreads();
        if (tid < 64) {
            u32 tot = sums_s[0][lane] + sums_s[1][lane] +
                      sums_s[2][lane] + sums_s[3][lane];
            u32 ct = cnt_s[0] + cnt_s[1] + cnt_s[2] + cnt_s[3];
            int g = (ct > 0u) && (2u * tot >= ct);
            u64 gm = __ballot(g);
            if (lane == 0) ((u64*)(ws + OFF_RES))[key] = gm;
        }
        __syncthreads();
    }
}

// K_D: per (q,d) gather 12 bits from the 256-bit agg vector, out-table bit test.
__global__ void __launch_bounds__(256) kD(const int* __restrict__ out_conn,
                                          const u8* __restrict__ ws,
                                          float* __restrict__ out) {
    int g = blockIdx.x * 256 + threadIdx.x;  // 0 .. NQ*DB-1
    int q = g >> 6, d = g & 63;
    const u16* aq = (const u16*)(ws + OFF_AQ);
    const u64* res = (const u64*)(ws + OFF_RES);
    u64 c0 = res[0 * 4096 + aq[0 * NQ + q]];
    u64 c1 = res[1 * 4096 + aq[1 * NQ + q]];
    u64 c2 = res[2 * 4096 + aq[2 * NQ + q]];
    u64 c3 = res[3 * 4096 + aq[3 * NQ + q]];
    int addr = 0;
#pragma unroll
    for (int j = 0; j < OUT_K; ++j) {
        int c = out_conn[d * OUT_K + j];
        u64 word = (c & 128) ? ((c & 64) ? c3 : c2) : ((c & 64) ? c1 : c0);
        addr |= (int)((word >> (c & 63)) & 1ull) << j;
    }
    u64 ow = ((const u64*)(ws + OFF_OUTTB))[(d << 6) + (addr >> 6)];
    out[g] = ((ow >> (addr & 63)) & 1ull) ? 1.0f : 0.0f;
}

extern "C" void kernel_launch(void* const* d_in, const int* in_sizes, int n_in,
                              void* d_out, int out_size, void* d_ws, size_t ws_size,
                              hipStream_t stream) {
    const int*   dec_bits  = (const int*)d_in[0];
    const int*   enc_bits  = (const int*)d_in[1];
    const int*   sim_conn  = (const int*)d_in[2];
    const float* sim_table = (const float*)d_in[3];
    const int*   val_conn  = (const int*)d_in[4];
    const float* val_table = (const float*)d_in[5];
    const int*   out_conn  = (const int*)d_in[6];
    const float* out_table = (const float*)d_in[7];
    float* out = (float*)d_out;
    u8* ws = (u8*)d_ws;

    hipLaunchKernelGGL(kA, dim3(64), dim3(256), 0, stream,
                       dec_bits, enc_bits, sim_conn, sim_table, val_table,
                       out_table, ws);
    hipLaunchKernelGGL(kB, dim3(256), dim3(256), 0, stream, val_conn, ws);
    hipLaunchKernelGGL(kC, dim3(2048), dim3(256), 0, stream, ws);
    hipLaunchKernelGGL(kD, dim3(NQ * DB / 256), dim3(256), 0, stream,
                       out_conn, ws, out);
}